// Round 9
// baseline (94.747 us; speedup 1.0000x reference)
//
#include <hip/hip_runtime.h>
#include <hip/hip_bf16.h>
#include <stdint.h>

// ---------------------------------------------------------------------------
// FMICL loss on MI355X — R18.
//   loss = -mean(s_pos) + 64 * ( sum_offdiag exp(-(2-2*G_ij)/2) / (N(N-1)) + 1e-8 )
//   G = Q @ Q^T, Q = fp4-e2m1(normalize(z1) * 32)  -- f8f6f4 MFMA, unit scales,
//   epilogue rescale g = acc / 1024. Gram symmetry makes any k-order / nibble
//   convention cancel between A and B.
//
// Attribution: R9=88.4 (4w), R13 (8w)=86.6 BEST, R17 (3blk/CU)=87.5 neutral,
// R11~R12 (drains 8 vs 4) = 0.0 delta -> drain COUNT irrelevant,
// R14 (no-LDS)=113.2 out, R15 (2-phase counted vmcnt)=90.7 out,
// R10/R16 (coop launch / atomic finalize) = container crashes -> abandoned.
//
// R18 = ONE structural change vs R13: stage the FULL K=1024 tile pair once
// (128 rows x 512 B x 2 = 128 KB LDS -- allowed on gfx950, cf. the 8-phase
// template's 128 KiB), then compute all 64 MFMAs/wave BARRIER-FREE.
// Exactly ONE vmcnt drain + ONE barrier per block (vs 4x[drain+2 barriers]).
// Tests the last surviving hypothesis: round-lockstep (not drain count, not
// occupancy, not staging) is gram's residual cost. 1 block/CU, 8 waves.
//
// LDS layout [128 rows][512 B]: 16B granule g of row r stored at slot
// g^(r&7) (XOR on low 3 bits; bijective per row). Read slot (kk*4+fq)^(r&7)
// returns granule kk*4+fq. Bank spread: slot&7 covers 8 values over the 16
// fr-lanes -> b128 reads touch all 32 banks 2-way = free (m136).
// global_load_lds dest stays linear in lane order (p = t + 512*j).
//
// ws layout: [0, 2MB) fp4 Q ; float spos[4096] ; float star[528]
// ---------------------------------------------------------------------------

#define AS1 __attribute__((address_space(1)))
#define AS3 __attribute__((address_space(3)))

typedef unsigned short u16;
typedef uint8_t  u8;
typedef int    i32x4 __attribute__((ext_vector_type(4)));
typedef int    i32x8 __attribute__((ext_vector_type(8)));
typedef float  f32x4 __attribute__((ext_vector_type(4)));

constexpr int   D     = 1024;         // feature dim == GEMM K (elements)
constexpr int   DB    = D / 2;        // Q row stride in BYTES (fp4) = 512
constexpr int   N     = 4096;         // rows per half
constexpr int   TM    = 128;          // tile M = tile N
constexpr int   NB    = N / TM;       // 32 tiles per side
constexpr int   NTRI  = NB * (NB + 1) / 2;  // 528 triangle tiles
constexpr float EPS   = 1e-8f;
constexpr float ALPHA = 64.0f;

__device__ __forceinline__ void async_load16(const void* g, void* l) {
    __builtin_amdgcn_global_load_lds((AS1 void*)g, (AS3 void*)l, 16, 0, 0);
}

// fp32 -> fp4 e2m1 nibble of round(|x|*32), sign bit 0x8.
__device__ __forceinline__ int fp4_of(float v) {
    const float y = fabsf(v) * 32.0f;
    int n = (y < 0.25f) ? 0 : (y < 0.75f) ? 1 : (y < 1.25f) ? 2 :
            (y < 1.75f) ? 3 : (y < 2.5f)  ? 4 : (y < 3.5f)  ? 5 :
            (y < 5.0f)  ? 6 : 7;
    return n | ((v < 0.0f) ? 8 : 0);
}

// ---------------------------------------------------------------------------
// Kernel 1: per row-pair i: normalize z1_i, z2_i (fp32), store fp4 Q row,
// compute s_pos_i -> spos[i]. Thread t packs elements [4t,4t+4) -> one u16.
// ---------------------------------------------------------------------------
__global__ __launch_bounds__(256) void norm_spos_kernel(
    const float* __restrict__ z, u8* __restrict__ q, float* __restrict__ spos)
{
    const int row = blockIdx.x;   // 0..4095
    const int t   = threadIdx.x;  // 0..255
    const int lane = t & 63, wave = t >> 6;

    const float4 a = ((const float4*)(z + (size_t)row       * D))[t];
    const float4 b = ((const float4*)(z + (size_t)(row + N) * D))[t];

    float s1 = a.x*a.x + a.y*a.y + a.z*a.z + a.w*a.w;
    float s2 = b.x*b.x + b.y*b.y + b.z*b.z + b.w*b.w;
    #pragma unroll
    for (int off = 32; off; off >>= 1) {
        s1 += __shfl_down(s1, off);
        s2 += __shfl_down(s2, off);
    }
    __shared__ float r1[4], r2[4], r3[4];
    if (lane == 0) { r1[wave] = s1; r2[wave] = s2; }
    __syncthreads();
    const float ss1 = r1[0] + r1[1] + r1[2] + r1[3];
    const float ss2 = r2[0] + r2[1] + r2[2] + r2[3];
    const float inv1 = 1.0f / fmaxf(sqrtf(ss1), 1e-12f);
    const float inv2 = 1.0f / fmaxf(sqrtf(ss2), 1e-12f);

    float4 an, bn;
    an.x = a.x * inv1; an.y = a.y * inv1; an.z = a.z * inv1; an.w = a.w * inv1;
    bn.x = b.x * inv2; bn.y = b.y * inv2; bn.z = b.z * inv2; bn.w = b.w * inv2;

    const int pk = fp4_of(an.x) | (fp4_of(an.y) << 4) |
                   (fp4_of(an.z) << 8) | (fp4_of(an.w) << 12);
    ((u16*)q)[row * (DB / 2) + t] = (u16)pk;

    const float dx = an.x - bn.x, dy = an.y - bn.y;
    const float dz = an.z - bn.z, dw = an.w - bn.w;
    float dp = dx*dx + dy*dy + dz*dz + dw*dw;
    #pragma unroll
    for (int off = 32; off; off >>= 1) dp += __shfl_down(dp, off);
    if (lane == 0) r3[wave] = dp;
    __syncthreads();
    if (t == 0) {
        const float d_pos = r3[0] + r3[1] + r3[2] + r3[3];
        const float g     = expf(-0.5f * d_pos);
        spos[row] = logf(g + EPS) + 1.0f;
    }
}

// ---------------------------------------------------------------------------
// Kernel 2: fused Gram + exp-sum over the (bi<=bj) triangle of 128x128 tiles.
// 512 threads = 8 waves in 2x4; each wave a 64x32 sub-tile = 4x2 of
// 16x16x128 fp4 MFMA (f8f6f4, cbsz=blgp=4, unit scales), 8 kk-steps = K=1024.
// Full-K staging: ONE drain + ONE barrier per block, then barrier-free MFMA
// phase (compiler-scheduled lgkmcnt interleave of 48 ds_read_b128 + 64 MFMA).
// ---------------------------------------------------------------------------
__global__ __launch_bounds__(512) void gram_kernel(
    const u8* __restrict__ Q, float* __restrict__ star_part)
{
    __shared__ __align__(16) u8 lA[TM * DB];  // 64 KB
    __shared__ __align__(16) u8 lB[TM * DB];  // 64 KB
    __shared__ float wsum[8];

    // triangle decode: blockIdx.x -> (bi, bj), bi <= bj
    int bi = 0, rem = blockIdx.x;
    while (rem >= NB - bi) { rem -= NB - bi; ++bi; }
    const int bj    = bi + rem;
    const int rowA0 = bi * TM, rowB0 = bj * TM;
    const bool diag = (bi == bj);

    const int t    = threadIdx.x;   // 0..511
    const int lane = t & 63;
    const int wave = t >> 6;        // 0..7
    const int wm   = (wave & 1) * 64;    // m-half
    const int wn   = (wave >> 1) * 32;   // n-quarter
    const int fr   = lane & 15;          // fragment row (m or n)
    const int fq   = lane >> 4;          // k-quad 0..3 (32 elements each)

    // Full-K staging: 4096 16B-granules per tile; thread handles p = t+512*j,
    // j = 0..7. Row r = p>>5 (32 granules/row), slot s = p&31, source granule
    // c = s ^ (r&7). LDS dest linear in lane order (wave-uniform + lane*16).
    #pragma unroll
    for (int j = 0; j < 8; ++j) {
        const int p = t + 512 * j;
        const int r = p >> 5;
        const int c = (p & 31) ^ (r & 7);
        async_load16(Q + (size_t)(rowA0 + r) * DB + c * 16, &lA[p * 16]);
        async_load16(Q + (size_t)(rowB0 + r) * DB + c * 16, &lB[p * 16]);
    }
    __syncthreads();   // the ONLY drain+barrier: all 16 loads/thread in LDS

    f32x4 acc[4][2];
    #pragma unroll
    for (int mt = 0; mt < 4; ++mt)
        #pragma unroll
        for (int nt = 0; nt < 2; ++nt)
            acc[mt][nt] = f32x4{0.f, 0.f, 0.f, 0.f};

    #pragma unroll
    for (int kk = 0; kk < 8; ++kk) {     // 8 x K=128 over the staged full-K
        i32x8 bf[2];
        #pragma unroll
        for (int nt = 0; nt < 2; ++nt) {
            const int r = wn + nt * 16 + fr;
            const i32x4 v = ((const i32x4*)&lB[r * DB])[(kk * 4 + fq) ^ (r & 7)];
            bf[nt][0] = v[0]; bf[nt][1] = v[1]; bf[nt][2] = v[2]; bf[nt][3] = v[3];
            bf[nt][4] = 0;    bf[nt][5] = 0;    bf[nt][6] = 0;    bf[nt][7] = 0;
        }
        #pragma unroll
        for (int mt = 0; mt < 4; ++mt) {
            const int r = wm + mt * 16 + fr;
            const i32x4 v = ((const i32x4*)&lA[r * DB])[(kk * 4 + fq) ^ (r & 7)];
            i32x8 af;
            af[0] = v[0]; af[1] = v[1]; af[2] = v[2]; af[3] = v[3];
            af[4] = 0;    af[5] = 0;    af[6] = 0;    af[7] = 0;
            #pragma unroll
            for (int nt = 0; nt < 2; ++nt)
                acc[mt][nt] = __builtin_amdgcn_mfma_scale_f32_16x16x128_f8f6f4(
                    af, bf[nt], acc[mt][nt],
                    4, 4,               // cbsz=fp4, blgp=fp4
                    0, 0x7f7f7f7f,      // scale A: e8m0 127 = 1.0
                    0, 0x7f7f7f7f);     // scale B
        }
    }

    // Epilogue: g = acc/1024 (undo 32x per-operand encoding);
    // e = exp(-max(2-2g,0)/2); diag tile masks i==j; off-diag x2.
    constexpr float INV = 1.0f / 1024.0f;
    float lsum = 0.0f;
    #pragma unroll
    for (int mt = 0; mt < 4; ++mt) {
        #pragma unroll
        for (int nt = 0; nt < 2; ++nt) {
            #pragma unroll
            for (int r = 0; r < 4; ++r) {
                const float g  = acc[mt][nt][r] * INV;
                const int   gi = wm + mt * 16 + fq * 4 + r;   // local row
                const int   gj = wn + nt * 16 + fr;           // local col
                const float d2 = fmaxf(2.0f - 2.0f * g, 0.0f);
                const float e  = __expf(-0.5f * d2);
                lsum += (diag && gi == gj) ? 0.0f : e;
            }
        }
    }
    #pragma unroll
    for (int off = 32; off; off >>= 1) lsum += __shfl_down(lsum, off);
    if (lane == 0) wsum[wave] = lsum;
    __syncthreads();
    if (t == 0) {
        float s = 0.0f;
        #pragma unroll
        for (int w = 0; w < 8; ++w) s += wsum[w];
        star_part[blockIdx.x] = (diag ? 1.0f : 2.0f) * s;
    }
}

// ---------------------------------------------------------------------------
// Kernel 3: sum the partials, assemble the scalar loss.
// ---------------------------------------------------------------------------
__global__ __launch_bounds__(256) void finalize_kernel(
    const float* __restrict__ spos, const float* __restrict__ star,
    float* __restrict__ out)
{
    const int t = threadIdx.x, lane = t & 63, wave = t >> 6;
    float s1 = 0.0f, s2 = 0.0f;
    for (int i = t; i < N;    i += 256) s1 += spos[i];
    for (int i = t; i < NTRI; i += 256) s2 += star[i];
    #pragma unroll
    for (int off = 32; off; off >>= 1) {
        s1 += __shfl_down(s1, off);
        s2 += __shfl_down(s2, off);
    }
    __shared__ float r1[4], r2[4];
    if (lane == 0) { r1[wave] = s1; r2[wave] = s2; }
    __syncthreads();
    if (t == 0) {
        const float spos_sum = r1[0] + r1[1] + r1[2] + r1[3];
        const float star_sum = r2[0] + r2[1] + r2[2] + r2[3];
        const float star_mean = star_sum / ((float)N * (float)(N - 1)) + EPS;
        out[0] = -spos_sum / (float)N + ALPHA * star_mean;
    }
}

// ---------------------------------------------------------------------------
extern "C" void kernel_launch(void* const* d_in, const int* in_sizes, int n_in,
                              void* d_out, int out_size, void* d_ws, size_t ws_size,
                              hipStream_t stream)
{
    (void)in_sizes; (void)n_in; (void)out_size; (void)ws_size;
    const float* z    = (const float*)d_in[0];
    float*       out  = (float*)d_out;
    u8*          q    = (u8*)d_ws;                                   // 2 MB fp4
    float*       spos = (float*)((char*)d_ws + (size_t)N * DB);      // 4096 f
    float*       star = spos + N;                                    // 528 f

    hipLaunchKernelGGL(norm_spos_kernel, dim3(N),    dim3(256), 0, stream, z, q, spos);
    hipLaunchKernelGGL(gram_kernel,      dim3(NTRI), dim3(512), 0, stream, q, star);
    hipLaunchKernelGGL(finalize_kernel,  dim3(1),    dim3(256), 0, stream, spos, star, out);
}

// Round 10
// 90.982 us; speedup vs baseline: 1.0414x; 1.0414x over previous
//
#include <hip/hip_runtime.h>
#include <hip/hip_bf16.h>
#include <stdint.h>

// ---------------------------------------------------------------------------
// FMICL loss on MI355X — R19.
//   loss = -mean(s_pos) + 64 * ( sum_offdiag exp(-(2-2*G_ij)/2) / (N(N-1)) + 1e-8 )
//   G = Q @ Q^T, Q = fp4-e2m1(normalize(z1) * 32)  -- f8f6f4 MFMA, unit scales,
//   epilogue rescale g = acc / 1024. Gram symmetry makes any k-order / nibble
//   convention cancel between A and B.
//
// Ledger: R9 (4w)=88.4, R13 (8w)=86.6 BEST, R17 (3blk/CU)=87.5, R11/R12
// (fence finalize +- dbuf)=95.5/95.3, R14 (no-LDS)=113.2, R15 (2-phase
// counted vmcnt)=90.7, R18 (full-K, 1blk/CU)=94.7 (confounded: LDS 128KB
// halved occupancy). Only positive: more waves. Plateau signature matches
// the m97-class structure ceiling (learn_hip m99-m141).
//
// R19 = R13 + ONE isolated change: BKB 128 -> 256 (2 staging rounds instead
// of 4) at CONSTANT occupancy (LDS 64 KB -> still 2 blocks/CU, 8 waves).
// Tests the last clean axis: drain-pair count x exposed L2 latency. Each
// round = 8 gload_lds/thread, then 32 MFMAs/wave between barriers.
//
// LDS tiles [128 rows][256 B]: 16B granule g of row r stored at slot g^(r&7)
// (slot in [0,16), XOR on low 3 bits -> bijective). Read slot (kk*4+fq)^(r&7),
// kk in [0,4). Bank spread 2-way over 8-row stripes = free (m136).
// global_load_lds dest stays linear in lane order (p = t + 512*j).
//
// ws layout: [0, 2MB) fp4 Q ; float spos[4096] ; float star[528]
// ---------------------------------------------------------------------------

#define AS1 __attribute__((address_space(1)))
#define AS3 __attribute__((address_space(3)))

typedef unsigned short u16;
typedef uint8_t  u8;
typedef int    i32x4 __attribute__((ext_vector_type(4)));
typedef int    i32x8 __attribute__((ext_vector_type(8)));
typedef float  f32x4 __attribute__((ext_vector_type(4)));

constexpr int   D     = 1024;         // feature dim == GEMM K (elements)
constexpr int   DB    = D / 2;        // Q row stride in BYTES (fp4) = 512
constexpr int   N     = 4096;         // rows per half
constexpr int   TM    = 128;          // tile M = tile N
constexpr int   BKB   = 256;          // K-step per staging round in BYTES (=512 elems)
constexpr int   NB    = N / TM;       // 32 tiles per side
constexpr int   NTRI  = NB * (NB + 1) / 2;  // 528 triangle tiles
constexpr float EPS   = 1e-8f;
constexpr float ALPHA = 64.0f;

__device__ __forceinline__ void async_load16(const void* g, void* l) {
    __builtin_amdgcn_global_load_lds((AS1 void*)g, (AS3 void*)l, 16, 0, 0);
}

// fp32 -> fp4 e2m1 nibble of round(|x|*32), sign bit 0x8.
__device__ __forceinline__ int fp4_of(float v) {
    const float y = fabsf(v) * 32.0f;
    int n = (y < 0.25f) ? 0 : (y < 0.75f) ? 1 : (y < 1.25f) ? 2 :
            (y < 1.75f) ? 3 : (y < 2.5f)  ? 4 : (y < 3.5f)  ? 5 :
            (y < 5.0f)  ? 6 : 7;
    return n | ((v < 0.0f) ? 8 : 0);
}

// ---------------------------------------------------------------------------
// Kernel 1: per row-pair i: normalize z1_i, z2_i (fp32), store fp4 Q row,
// compute s_pos_i -> spos[i]. Thread t packs elements [4t,4t+4) -> one u16.
// ---------------------------------------------------------------------------
__global__ __launch_bounds__(256) void norm_spos_kernel(
    const float* __restrict__ z, u8* __restrict__ q, float* __restrict__ spos)
{
    const int row = blockIdx.x;   // 0..4095
    const int t   = threadIdx.x;  // 0..255
    const int lane = t & 63, wave = t >> 6;

    const float4 a = ((const float4*)(z + (size_t)row       * D))[t];
    const float4 b = ((const float4*)(z + (size_t)(row + N) * D))[t];

    float s1 = a.x*a.x + a.y*a.y + a.z*a.z + a.w*a.w;
    float s2 = b.x*b.x + b.y*b.y + b.z*b.z + b.w*b.w;
    #pragma unroll
    for (int off = 32; off; off >>= 1) {
        s1 += __shfl_down(s1, off);
        s2 += __shfl_down(s2, off);
    }
    __shared__ float r1[4], r2[4], r3[4];
    if (lane == 0) { r1[wave] = s1; r2[wave] = s2; }
    __syncthreads();
    const float ss1 = r1[0] + r1[1] + r1[2] + r1[3];
    const float ss2 = r2[0] + r2[1] + r2[2] + r2[3];
    const float inv1 = 1.0f / fmaxf(sqrtf(ss1), 1e-12f);
    const float inv2 = 1.0f / fmaxf(sqrtf(ss2), 1e-12f);

    float4 an, bn;
    an.x = a.x * inv1; an.y = a.y * inv1; an.z = a.z * inv1; an.w = a.w * inv1;
    bn.x = b.x * inv2; bn.y = b.y * inv2; bn.z = b.z * inv2; bn.w = b.w * inv2;

    const int pk = fp4_of(an.x) | (fp4_of(an.y) << 4) |
                   (fp4_of(an.z) << 8) | (fp4_of(an.w) << 12);
    ((u16*)q)[row * (DB / 2) + t] = (u16)pk;

    const float dx = an.x - bn.x, dy = an.y - bn.y;
    const float dz = an.z - bn.z, dw = an.w - bn.w;
    float dp = dx*dx + dy*dy + dz*dz + dw*dw;
    #pragma unroll
    for (int off = 32; off; off >>= 1) dp += __shfl_down(dp, off);
    if (lane == 0) r3[wave] = dp;
    __syncthreads();
    if (t == 0) {
        const float d_pos = r3[0] + r3[1] + r3[2] + r3[3];
        const float g     = expf(-0.5f * d_pos);
        spos[row] = logf(g + EPS) + 1.0f;
    }
}

// ---------------------------------------------------------------------------
// Kernel 2: fused Gram + exp-sum over the (bi<=bj) triangle of 128x128 tiles.
// 512 threads = 8 waves in 2x4; each wave a 64x32 sub-tile = 4x2 of
// 16x16x128 fp4 MFMA (f8f6f4, cbsz=blgp=4, unit scales). 2 K-rounds of 512
// elements (256 B); 32 MFMAs/wave between barrier pairs.
// ---------------------------------------------------------------------------
__global__ __launch_bounds__(512, 4) void gram_kernel(
    const u8* __restrict__ Q, float* __restrict__ star_part)
{
    __shared__ __align__(16) u8 lA[TM * BKB];  // 32 KB
    __shared__ __align__(16) u8 lB[TM * BKB];  // 32 KB
    __shared__ float wsum[8];

    // triangle decode: blockIdx.x -> (bi, bj), bi <= bj
    int bi = 0, rem = blockIdx.x;
    while (rem >= NB - bi) { rem -= NB - bi; ++bi; }
    const int bj    = bi + rem;
    const int rowA0 = bi * TM, rowB0 = bj * TM;
    const bool diag = (bi == bj);

    const int t    = threadIdx.x;   // 0..511
    const int lane = t & 63;
    const int wave = t >> 6;        // 0..7
    const int wm   = (wave & 1) * 64;    // m-half
    const int wn   = (wave >> 1) * 32;   // n-quarter
    const int fr   = lane & 15;          // fragment row (m or n)
    const int fq   = lane >> 4;          // k-quad 0..3 (32 elements each)

    // staging: 2048 16B-granules per tile per round; thread handles
    // p = t + 512*j, j = 0..3. Row r = p>>4 (16 granules/row), slot s = p&15,
    // source granule c = s ^ (r&7) (self-inverse; dest linear in lane order).
    const u8* gA[4]; const u8* gB[4]; u8* dA[4]; u8* dB[4];
    #pragma unroll
    for (int j = 0; j < 4; ++j) {
        const int p = t + 512 * j;
        const int r = p >> 4;
        const int c = (p & 15) ^ (r & 7);
        gA[j] = Q + (size_t)(rowA0 + r) * DB + c * 16;
        gB[j] = Q + (size_t)(rowB0 + r) * DB + c * 16;
        dA[j] = &lA[p * 16];
        dB[j] = &lB[p * 16];
    }

    f32x4 acc[4][2];
    #pragma unroll
    for (int mt = 0; mt < 4; ++mt)
        #pragma unroll
        for (int nt = 0; nt < 2; ++nt)
            acc[mt][nt] = f32x4{0.f, 0.f, 0.f, 0.f};

    for (int k0 = 0; k0 < DB; k0 += BKB) {   // 2 rounds (byte offset in row)
        #pragma unroll
        for (int j = 0; j < 4; ++j) {
            async_load16(gA[j] + k0, dA[j]);
            async_load16(gB[j] + k0, dB[j]);
        }
        __syncthreads();   // drains vmcnt for the LDS-DMA

        #pragma unroll
        for (int kk = 0; kk < 4; ++kk) {     // four K=128 MFMA steps per round
            i32x8 bf[2];
            #pragma unroll
            for (int nt = 0; nt < 2; ++nt) {
                const int r = wn + nt * 16 + fr;
                const i32x4 v = ((const i32x4*)&lB[r * BKB])[(kk * 4 + fq) ^ (r & 7)];
                bf[nt][0] = v[0]; bf[nt][1] = v[1]; bf[nt][2] = v[2]; bf[nt][3] = v[3];
                bf[nt][4] = 0;    bf[nt][5] = 0;    bf[nt][6] = 0;    bf[nt][7] = 0;
            }
            #pragma unroll
            for (int mt = 0; mt < 4; ++mt) {
                const int r = wm + mt * 16 + fr;
                const i32x4 v = ((const i32x4*)&lA[r * BKB])[(kk * 4 + fq) ^ (r & 7)];
                i32x8 af;
                af[0] = v[0]; af[1] = v[1]; af[2] = v[2]; af[3] = v[3];
                af[4] = 0;    af[5] = 0;    af[6] = 0;    af[7] = 0;
                #pragma unroll
                for (int nt = 0; nt < 2; ++nt)
                    acc[mt][nt] = __builtin_amdgcn_mfma_scale_f32_16x16x128_f8f6f4(
                        af, bf[nt], acc[mt][nt],
                        4, 4,               // cbsz=fp4, blgp=fp4
                        0, 0x7f7f7f7f,      // scale A: e8m0 127 = 1.0
                        0, 0x7f7f7f7f);     // scale B
            }
        }

        __syncthreads();   // protect LDS before next staging round
    }

    // Epilogue: g = acc/1024 (undo 32x per-operand encoding);
    // e = exp(-max(2-2g,0)/2); diag tile masks i==j; off-diag x2.
    constexpr float INV = 1.0f / 1024.0f;
    float lsum = 0.0f;
    #pragma unroll
    for (int mt = 0; mt < 4; ++mt) {
        #pragma unroll
        for (int nt = 0; nt < 2; ++nt) {
            #pragma unroll
            for (int r = 0; r < 4; ++r) {
                const float g  = acc[mt][nt][r] * INV;
                const int   gi = wm + mt * 16 + fq * 4 + r;   // local row
                const int   gj = wn + nt * 16 + fr;           // local col
                const float d2 = fmaxf(2.0f - 2.0f * g, 0.0f);
                const float e  = __expf(-0.5f * d2);
                lsum += (diag && gi == gj) ? 0.0f : e;
            }
        }
    }
    #pragma unroll
    for (int off = 32; off; off >>= 1) lsum += __shfl_down(lsum, off);
    if (lane == 0) wsum[wave] = lsum;
    __syncthreads();
    if (t == 0) {
        float s = 0.0f;
        #pragma unroll
        for (int w = 0; w < 8; ++w) s += wsum[w];
        star_part[blockIdx.x] = (diag ? 1.0f : 2.0f) * s;
    }
}

// ---------------------------------------------------------------------------
// Kernel 3: sum the partials, assemble the scalar loss.
// ---------------------------------------------------------------------------
__global__ __launch_bounds__(256) void finalize_kernel(
    const float* __restrict__ spos, const float* __restrict__ star,
    float* __restrict__ out)
{
    const int t = threadIdx.x, lane = t & 63, wave = t >> 6;
    float s1 = 0.0f, s2 = 0.0f;
    for (int i = t; i < N;    i += 256) s1 += spos[i];
    for (int i = t; i < NTRI; i += 256) s2 += star[i];
    #pragma unroll
    for (int off = 32; off; off >>= 1) {
        s1 += __shfl_down(s1, off);
        s2 += __shfl_down(s2, off);
    }
    __shared__ float r1[4], r2[4];
    if (lane == 0) { r1[wave] = s1; r2[wave] = s2; }
    __syncthreads();
    if (t == 0) {
        const float spos_sum = r1[0] + r1[1] + r1[2] + r1[3];
        const float star_sum = r2[0] + r2[1] + r2[2] + r2[3];
        const float star_mean = star_sum / ((float)N * (float)(N - 1)) + EPS;
        out[0] = -spos_sum / (float)N + ALPHA * star_mean;
    }
}

// ---------------------------------------------------------------------------
extern "C" void kernel_launch(void* const* d_in, const int* in_sizes, int n_in,
                              void* d_out, int out_size, void* d_ws, size_t ws_size,
                              hipStream_t stream)
{
    (void)in_sizes; (void)n_in; (void)out_size; (void)ws_size;
    const float* z    = (const float*)d_in[0];
    float*       out  = (float*)d_out;
    u8*          q    = (u8*)d_ws;                                   // 2 MB fp4
    float*       spos = (float*)((char*)d_ws + (size_t)N * DB);      // 4096 f
    float*       star = spos + N;                                    // 528 f

    hipLaunchKernelGGL(norm_spos_kernel, dim3(N),    dim3(256), 0, stream, z, q, spos);
    hipLaunchKernelGGL(gram_kernel,      dim3(NTRI), dim3(512), 0, stream, q, star);
    hipLaunchKernelGGL(finalize_kernel,  dim3(1),    dim3(256), 0, stream, spos, star, out);
}

// Round 11
// 90.155 us; speedup vs baseline: 1.0509x; 1.0092x over previous
//
#include <hip/hip_runtime.h>
#include <hip/hip_bf16.h>
#include <stdint.h>

// ---------------------------------------------------------------------------
// FMICL loss on MI355X — R20.
//   loss = -mean(s_pos) + 64 * ( sum_offdiag exp(-(2-2*G_ij)/2) / (N(N-1)) + 1e-8 )
//   G = Q @ Q^T, Q = fp4-e2m1(normalize(z1) * 32)  -- f8f6f4 MFMA, unit scales,
//   epilogue rescale g = acc / 1024. Gram symmetry makes any k-order / nibble
//   convention cancel between A and B.
//
// Ledger: R13 (128-tile, 8w, 2blk/CU)=86.6 BEST; R9 (4w)=88.4; R17
// (3blk/CU diet)=87.5; R19 (BKB=256)=91.0; R18 (full-K 1blk/CU)=94.7;
// R15 (counted vmcnt)=90.7; R11/R12 (fence finalize)=95.5/95.3;
// R14 (no-LDS)=113.2. Pattern: gram is DRAIN-LATENCY-bound; only raising
// independent-warp coverage ever helped (R9->R13).
//
// R20 = tile 128 -> 64 (NB=64, NTRI=2080 blocks, 4-wave blocks, 16 KB LDS,
// SAME BKB=128 / 4-round / 2-barrier structure & swizzle algebra verbatim):
// ~68 VGPR + launch_bounds(256,6) -> ~6-7 blocks/CU = 24-28 waves/CU
// (vs R13's 16), 4x finer makespan granularity. Cost: staged L2 traffic
// 67.6 -> 133 MB (~+2us overlappable) -- cheap if drain-bound theory holds.
//
// ws layout: [0, 2MB) fp4 Q ; float spos[4096] ; float star[2080]
// ---------------------------------------------------------------------------

#define AS1 __attribute__((address_space(1)))
#define AS3 __attribute__((address_space(3)))

typedef unsigned short u16;
typedef uint8_t  u8;
typedef int    i32x4 __attribute__((ext_vector_type(4)));
typedef int    i32x8 __attribute__((ext_vector_type(8)));
typedef float  f32x4 __attribute__((ext_vector_type(4)));

constexpr int   D     = 1024;         // feature dim == GEMM K (elements)
constexpr int   DB    = D / 2;        // Q row stride in BYTES (fp4) = 512
constexpr int   N     = 4096;         // rows per half
constexpr int   TM    = 64;           // tile M = tile N
constexpr int   BKB   = 128;          // K-step per staging round in BYTES (=256 elems)
constexpr int   NB    = N / TM;       // 64 tiles per side
constexpr int   NTRI  = NB * (NB + 1) / 2;  // 2080 triangle tiles
constexpr float EPS   = 1e-8f;
constexpr float ALPHA = 64.0f;

__device__ __forceinline__ void async_load16(const void* g, void* l) {
    __builtin_amdgcn_global_load_lds((AS1 void*)g, (AS3 void*)l, 16, 0, 0);
}

// fp32 -> fp4 e2m1 nibble of round(|x|*32), sign bit 0x8.
__device__ __forceinline__ int fp4_of(float v) {
    const float y = fabsf(v) * 32.0f;
    int n = (y < 0.25f) ? 0 : (y < 0.75f) ? 1 : (y < 1.25f) ? 2 :
            (y < 1.75f) ? 3 : (y < 2.5f)  ? 4 : (y < 3.5f)  ? 5 :
            (y < 5.0f)  ? 6 : 7;
    return n | ((v < 0.0f) ? 8 : 0);
}

// ---------------------------------------------------------------------------
// Kernel 1: per row-pair i: normalize z1_i, z2_i (fp32), store fp4 Q row,
// compute s_pos_i -> spos[i]. Thread t packs elements [4t,4t+4) -> one u16.
// ---------------------------------------------------------------------------
__global__ __launch_bounds__(256) void norm_spos_kernel(
    const float* __restrict__ z, u8* __restrict__ q, float* __restrict__ spos)
{
    const int row = blockIdx.x;   // 0..4095
    const int t   = threadIdx.x;  // 0..255
    const int lane = t & 63, wave = t >> 6;

    const float4 a = ((const float4*)(z + (size_t)row       * D))[t];
    const float4 b = ((const float4*)(z + (size_t)(row + N) * D))[t];

    float s1 = a.x*a.x + a.y*a.y + a.z*a.z + a.w*a.w;
    float s2 = b.x*b.x + b.y*b.y + b.z*b.z + b.w*b.w;
    #pragma unroll
    for (int off = 32; off; off >>= 1) {
        s1 += __shfl_down(s1, off);
        s2 += __shfl_down(s2, off);
    }
    __shared__ float r1[4], r2[4], r3[4];
    if (lane == 0) { r1[wave] = s1; r2[wave] = s2; }
    __syncthreads();
    const float ss1 = r1[0] + r1[1] + r1[2] + r1[3];
    const float ss2 = r2[0] + r2[1] + r2[2] + r2[3];
    const float inv1 = 1.0f / fmaxf(sqrtf(ss1), 1e-12f);
    const float inv2 = 1.0f / fmaxf(sqrtf(ss2), 1e-12f);

    float4 an, bn;
    an.x = a.x * inv1; an.y = a.y * inv1; an.z = a.z * inv1; an.w = a.w * inv1;
    bn.x = b.x * inv2; bn.y = b.y * inv2; bn.z = b.z * inv2; bn.w = b.w * inv2;

    const int pk = fp4_of(an.x) | (fp4_of(an.y) << 4) |
                   (fp4_of(an.z) << 8) | (fp4_of(an.w) << 12);
    ((u16*)q)[row * (DB / 2) + t] = (u16)pk;

    const float dx = an.x - bn.x, dy = an.y - bn.y;
    const float dz = an.z - bn.z, dw = an.w - bn.w;
    float dp = dx*dx + dy*dy + dz*dz + dw*dw;
    #pragma unroll
    for (int off = 32; off; off >>= 1) dp += __shfl_down(dp, off);
    if (lane == 0) r3[wave] = dp;
    __syncthreads();
    if (t == 0) {
        const float d_pos = r3[0] + r3[1] + r3[2] + r3[3];
        const float g     = expf(-0.5f * d_pos);
        spos[row] = logf(g + EPS) + 1.0f;
    }
}

// ---------------------------------------------------------------------------
// Kernel 2: fused Gram + exp-sum over the (bi<=bj) triangle of 64x64 tiles.
// 256 threads = 4 waves in 2x2; each wave a 32x32 sub-tile = 2x2 of
// 16x16x128 fp4 MFMA (f8f6f4, cbsz=blgp=4, unit scales). 4 K-rounds of 256
// elements (128 B), 2 kk-steps per round (R13 structure at TM=64).
//
// LDS tiles [64 rows][128 B]: 16B granule g of row r stored at slot g^(r&7).
// global_load_lds dest stays linear in lane order; only the global SOURCE
// granule is permuted. Fragment = ONE b128 per lane (16 B = 32 fp4 = K-slice).
// ---------------------------------------------------------------------------
__global__ __launch_bounds__(256, 6) void gram_kernel(
    const u8* __restrict__ Q, float* __restrict__ star_part)
{
    __shared__ __align__(16) u8 lA[TM * BKB];  // 8 KB
    __shared__ __align__(16) u8 lB[TM * BKB];  // 8 KB
    __shared__ float wsum[4];

    // triangle decode: blockIdx.x -> (bi, bj), bi <= bj
    int bi = 0, rem = blockIdx.x;
    while (rem >= NB - bi) { rem -= NB - bi; ++bi; }
    const int bj    = bi + rem;
    const int rowA0 = bi * TM, rowB0 = bj * TM;
    const bool diag = (bi == bj);

    const int t    = threadIdx.x;   // 0..255
    const int lane = t & 63;
    const int wave = t >> 6;        // 0..3
    const int wm   = (wave & 1) * 32;    // m-half
    const int wn   = (wave >> 1) * 32;   // n-half
    const int fr   = lane & 15;          // fragment row (m or n)
    const int fq   = lane >> 4;          // k-quad 0..3 (32 elements each)

    // staging: 512 16B-granules per tile per round; thread handles
    // p = t + 256*j, j = 0..1. Row r = p>>3 (8 granules/row), slot s = p&7,
    // source granule c = s ^ (r&7) (self-inverse; dest linear in lane order).
    const u8* gA[2]; const u8* gB[2]; u8* dA[2]; u8* dB[2];
    #pragma unroll
    for (int j = 0; j < 2; ++j) {
        const int p = t + 256 * j;
        const int r = p >> 3;
        const int c = (p & 7) ^ (r & 7);
        gA[j] = Q + (size_t)(rowA0 + r) * DB + c * 16;
        gB[j] = Q + (size_t)(rowB0 + r) * DB + c * 16;
        dA[j] = &lA[p * 16];
        dB[j] = &lB[p * 16];
    }

    f32x4 acc[2][2];
    #pragma unroll
    for (int mt = 0; mt < 2; ++mt)
        #pragma unroll
        for (int nt = 0; nt < 2; ++nt)
            acc[mt][nt] = f32x4{0.f, 0.f, 0.f, 0.f};

    for (int k0 = 0; k0 < DB; k0 += BKB) {   // 4 rounds (byte offset in row)
        #pragma unroll
        for (int j = 0; j < 2; ++j) {
            async_load16(gA[j] + k0, dA[j]);
            async_load16(gB[j] + k0, dB[j]);
        }
        __syncthreads();   // drains vmcnt for the LDS-DMA

        #pragma unroll
        for (int kk = 0; kk < 2; ++kk) {     // two K=128 MFMA steps per round
            i32x8 bf[2];
            #pragma unroll
            for (int nt = 0; nt < 2; ++nt) {
                const int r = wn + nt * 16 + fr;
                const i32x4 v = ((const i32x4*)&lB[r * BKB])[(kk * 4 + fq) ^ (r & 7)];
                bf[nt][0] = v[0]; bf[nt][1] = v[1]; bf[nt][2] = v[2]; bf[nt][3] = v[3];
                bf[nt][4] = 0;    bf[nt][5] = 0;    bf[nt][6] = 0;    bf[nt][7] = 0;
            }
            #pragma unroll
            for (int mt = 0; mt < 2; ++mt) {
                const int r = wm + mt * 16 + fr;
                const i32x4 v = ((const i32x4*)&lA[r * BKB])[(kk * 4 + fq) ^ (r & 7)];
                i32x8 af;
                af[0] = v[0]; af[1] = v[1]; af[2] = v[2]; af[3] = v[3];
                af[4] = 0;    af[5] = 0;    af[6] = 0;    af[7] = 0;
                #pragma unroll
                for (int nt = 0; nt < 2; ++nt)
                    acc[mt][nt] = __builtin_amdgcn_mfma_scale_f32_16x16x128_f8f6f4(
                        af, bf[nt], acc[mt][nt],
                        4, 4,               // cbsz=fp4, blgp=fp4
                        0, 0x7f7f7f7f,      // scale A: e8m0 127 = 1.0
                        0, 0x7f7f7f7f);     // scale B
            }
        }

        __syncthreads();   // protect LDS before next staging round
    }

    // Epilogue: g = acc/1024 (undo 32x per-operand encoding);
    // e = exp(-max(2-2g,0)/2); diag tile masks i==j; off-diag x2.
    constexpr float INV = 1.0f / 1024.0f;
    float lsum = 0.0f;
    #pragma unroll
    for (int mt = 0; mt < 2; ++mt) {
        #pragma unroll
        for (int nt = 0; nt < 2; ++nt) {
            #pragma unroll
            for (int r = 0; r < 4; ++r) {
                const float g  = acc[mt][nt][r] * INV;
                const int   gi = wm + mt * 16 + fq * 4 + r;   // local row
                const int   gj = wn + nt * 16 + fr;           // local col
                const float d2 = fmaxf(2.0f - 2.0f * g, 0.0f);
                const float e  = __expf(-0.5f * d2);
                lsum += (diag && gi == gj) ? 0.0f : e;
            }
        }
    }
    #pragma unroll
    for (int off = 32; off; off >>= 1) lsum += __shfl_down(lsum, off);
    if (lane == 0) wsum[wave] = lsum;
    __syncthreads();
    if (t == 0) {
        star_part[blockIdx.x] = (diag ? 1.0f : 2.0f) *
                                (wsum[0] + wsum[1] + wsum[2] + wsum[3]);
    }
}

// ---------------------------------------------------------------------------
// Kernel 3: sum the partials, assemble the scalar loss.
// ---------------------------------------------------------------------------
__global__ __launch_bounds__(256) void finalize_kernel(
    const float* __restrict__ spos, const float* __restrict__ star,
    float* __restrict__ out)
{
    const int t = threadIdx.x, lane = t & 63, wave = t >> 6;
    float s1 = 0.0f, s2 = 0.0f;
    for (int i = t; i < N;    i += 256) s1 += spos[i];
    for (int i = t; i < NTRI; i += 256) s2 += star[i];
    #pragma unroll
    for (int off = 32; off; off >>= 1) {
        s1 += __shfl_down(s1, off);
        s2 += __shfl_down(s2, off);
    }
    __shared__ float r1[4], r2[4];
    if (lane == 0) { r1[wave] = s1; r2[wave] = s2; }
    __syncthreads();
    if (t == 0) {
        const float spos_sum = r1[0] + r1[1] + r1[2] + r1[3];
        const float star_sum = r2[0] + r2[1] + r2[2] + r2[3];
        const float star_mean = star_sum / ((float)N * (float)(N - 1)) + EPS;
        out[0] = -spos_sum / (float)N + ALPHA * star_mean;
    }
}

// ---------------------------------------------------------------------------
extern "C" void kernel_launch(void* const* d_in, const int* in_sizes, int n_in,
                              void* d_out, int out_size, void* d_ws, size_t ws_size,
                              hipStream_t stream)
{
    (void)in_sizes; (void)n_in; (void)out_size; (void)ws_size;
    const float* z    = (const float*)d_in[0];
    float*       out  = (float*)d_out;
    u8*          q    = (u8*)d_ws;                                   // 2 MB fp4
    float*       spos = (float*)((char*)d_ws + (size_t)N * DB);      // 4096 f
    float*       star = spos + N;                                    // 2080 f

    hipLaunchKernelGGL(norm_spos_kernel, dim3(N),    dim3(256), 0, stream, z, q, spos);
    hipLaunchKernelGGL(gram_kernel,      dim3(NTRI), dim3(256), 0, stream, q, star);
    hipLaunchKernelGGL(finalize_kernel,  dim3(1),    dim3(256), 0, stream, spos, star, out);
}

// Round 12
// 89.823 us; speedup vs baseline: 1.0548x; 1.0037x over previous
//
#include <hip/hip_runtime.h>
#include <hip/hip_bf16.h>
#include <stdint.h>

// ---------------------------------------------------------------------------
// FMICL loss on MI355X — R21.
//   loss = -mean(s_pos) + 64 * ( sum_offdiag exp(-(2-2*G_ij)/2) / (N(N-1)) + 1e-8 )
//   G = Q @ Q^T, Q = fp4-e2m1(normalize(z1) * 32)  -- f8f6f4 MFMA, unit scales,
//   epilogue rescale g = acc / 1024. Gram symmetry makes any k-order / nibble
//   convention cancel between A and B.
//
// Ledger (gram axes all closed; R13 gram = plateau best):
//   R13 (128-tile, 8w, 2blk/CU, 4 rounds)=86.6 BEST; R9 (4w)=88.4;
//   R17 (3blk/CU)=87.5; R18 (full-K 1blk/CU)=94.7; R19 (BKB=256)=91.0;
//   R20 (64-tile hi-occ)=90.2; R15 (counted vmcnt)=90.7; R14 (no-LDS)=113.2;
//   R11/R12/R16 (fusion attempts)=95.5/95.3/crash. m97-class structural
//   plateau (learn_hip m99-m141): vmcnt-drain-before-barrier is the residue.
//
// R21 = R13 gram VERBATIM + norm rewritten wave-per-row (the one kernel
// never optimized): one wave owns one row pair; 16 contiguous floats/lane
// /row (4x float4, dense 4KB/wave/instr); __shfl_xor reductions ONLY --
// zero barriers, zero LDS; packed ushort4 store (8B/lane coalesced).
// Q byte layout identical to R13 (same element->nibble->u16 map).
//
// ws layout: [0, 2MB) fp4 Q ; float spos[4096] ; float star[528]
// ---------------------------------------------------------------------------

#define AS1 __attribute__((address_space(1)))
#define AS3 __attribute__((address_space(3)))

typedef unsigned short u16;
typedef uint8_t  u8;
typedef int    i32x4 __attribute__((ext_vector_type(4)));
typedef int    i32x8 __attribute__((ext_vector_type(8)));
typedef float  f32x4 __attribute__((ext_vector_type(4)));

constexpr int   D     = 1024;         // feature dim == GEMM K (elements)
constexpr int   DB    = D / 2;        // Q row stride in BYTES (fp4) = 512
constexpr int   N     = 4096;         // rows per half
constexpr int   TM    = 128;          // tile M = tile N
constexpr int   BKB   = 128;          // K-step per staging round in BYTES (=256 elems)
constexpr int   NB    = N / TM;       // 32 tiles per side
constexpr int   NTRI  = NB * (NB + 1) / 2;  // 528 triangle tiles
constexpr float EPS   = 1e-8f;
constexpr float ALPHA = 64.0f;

__device__ __forceinline__ void async_load16(const void* g, void* l) {
    __builtin_amdgcn_global_load_lds((AS1 void*)g, (AS3 void*)l, 16, 0, 0);
}

// fp32 -> fp4 e2m1 nibble of round(|x|*32), sign bit 0x8.
__device__ __forceinline__ int fp4_of(float v) {
    const float y = fabsf(v) * 32.0f;
    int n = (y < 0.25f) ? 0 : (y < 0.75f) ? 1 : (y < 1.25f) ? 2 :
            (y < 1.75f) ? 3 : (y < 2.5f)  ? 4 : (y < 3.5f)  ? 5 :
            (y < 5.0f)  ? 6 : 7;
    return n | ((v < 0.0f) ? 8 : 0);
}

// ---------------------------------------------------------------------------
// Kernel 1 (wave-per-row rewrite): wave w of block b owns row pair
// r = b*4 + w. Lane l holds elements [l*16, l*16+16) of z1_r and z2_r
// (4x float4 each, dense). Shuffle-xor reductions; no LDS, no barriers.
// Packs 16 elements -> 4 u16 -> one ushort4 store at q + r*512 + l*8.
// ---------------------------------------------------------------------------
__global__ __launch_bounds__(256) void norm_spos_kernel(
    const float* __restrict__ z, u8* __restrict__ q, float* __restrict__ spos)
{
    const int lane = threadIdx.x & 63;
    const int wave = threadIdx.x >> 6;
    const int row  = blockIdx.x * 4 + wave;   // 1024 blocks x 4 waves = 4096

    const float4* pa = (const float4*)(z + (size_t)row       * D);
    const float4* pb = (const float4*)(z + (size_t)(row + N) * D);

    float4 a[4], b[4];
    #pragma unroll
    for (int j = 0; j < 4; ++j) {
        a[j] = pa[lane * 4 + j];
        b[j] = pb[lane * 4 + j];
    }

    float s1 = 0.0f, s2 = 0.0f;
    #pragma unroll
    for (int j = 0; j < 4; ++j) {
        s1 += a[j].x*a[j].x + a[j].y*a[j].y + a[j].z*a[j].z + a[j].w*a[j].w;
        s2 += b[j].x*b[j].x + b[j].y*b[j].y + b[j].z*b[j].z + b[j].w*b[j].w;
    }
    #pragma unroll
    for (int off = 32; off; off >>= 1) {
        s1 += __shfl_xor(s1, off);
        s2 += __shfl_xor(s2, off);
    }
    const float inv1 = 1.0f / fmaxf(sqrtf(s1), 1e-12f);
    const float inv2 = 1.0f / fmaxf(sqrtf(s2), 1e-12f);

    // normalize, pack fp4 nibbles (row a), accumulate |an-bn|^2
    u16 pk[4];
    float dp = 0.0f;
    #pragma unroll
    for (int j = 0; j < 4; ++j) {
        const float ax = a[j].x * inv1, ay = a[j].y * inv1;
        const float az = a[j].z * inv1, aw = a[j].w * inv1;
        const float bx = b[j].x * inv2, by = b[j].y * inv2;
        const float bz = b[j].z * inv2, bw = b[j].w * inv2;
        pk[j] = (u16)(fp4_of(ax) | (fp4_of(ay) << 4) |
                      (fp4_of(az) << 8) | (fp4_of(aw) << 12));
        const float dx = ax - bx, dy = ay - by, dz = az - bz, dw = aw - bw;
        dp += dx*dx + dy*dy + dz*dz + dw*dw;
    }
    // coalesced 8B/lane store: ushort4 index lane within the 512B row
    ushort4 v; v.x = pk[0]; v.y = pk[1]; v.z = pk[2]; v.w = pk[3];
    ((ushort4*)(q + (size_t)row * DB))[lane] = v;

    #pragma unroll
    for (int off = 32; off; off >>= 1) dp += __shfl_xor(dp, off);
    if (lane == 0) {
        const float g = expf(-0.5f * dp);
        spos[row] = logf(g + EPS) + 1.0f;
    }
}

// ---------------------------------------------------------------------------
// Kernel 2 (R13 verbatim): fused Gram + exp-sum over the (bi<=bj) triangle
// of 128x128 tiles. 512 threads = 8 waves in 2x4; each wave a 64x32
// sub-tile = 4x2 of 16x16x128 fp4 MFMA (f8f6f4, cbsz=blgp=4, unit scales).
// 4 K-iters of 256 elements (128 B).
//
// LDS tiles [128 rows][128 B]: 16B granule g of row r stored at slot g^(r&7).
// global_load_lds dest stays linear in lane order; only the global SOURCE
// granule is permuted. Fragment = ONE b128 per lane (16 B = 32 fp4 = K-slice).
// ---------------------------------------------------------------------------
__global__ __launch_bounds__(512, 4) void gram_kernel(
    const u8* __restrict__ Q, float* __restrict__ star_part)
{
    __shared__ __align__(16) u8 lA[TM * BKB];  // 16 KB
    __shared__ __align__(16) u8 lB[TM * BKB];  // 16 KB
    __shared__ float wsum[8];

    // triangle decode: blockIdx.x -> (bi, bj), bi <= bj
    int bi = 0, rem = blockIdx.x;
    while (rem >= NB - bi) { rem -= NB - bi; ++bi; }
    const int bj    = bi + rem;
    const int rowA0 = bi * TM, rowB0 = bj * TM;
    const bool diag = (bi == bj);

    const int t    = threadIdx.x;   // 0..511
    const int lane = t & 63;
    const int wave = t >> 6;        // 0..7
    const int wm   = (wave & 1) * 64;    // m-half
    const int wn   = (wave >> 1) * 32;   // n-quarter
    const int fr   = lane & 15;          // fragment row (m or n)
    const int fq   = lane >> 4;          // k-quad 0..3 (32 elements each)

    // staging: 1024 16B-granules per tile, thread handles p = t + 512*j
    const u8* gA[2]; const u8* gB[2]; u8* dA[2]; u8* dB[2];
    #pragma unroll
    for (int j = 0; j < 2; ++j) {
        const int p = t + 512 * j;
        const int r = p >> 3;
        const int c = (p & 7) ^ (r & 7);   // XOR swizzle (self-inverse)
        gA[j] = Q + (size_t)(rowA0 + r) * DB + c * 16;
        gB[j] = Q + (size_t)(rowB0 + r) * DB + c * 16;
        dA[j] = &lA[p * 16];
        dB[j] = &lB[p * 16];
    }

    f32x4 acc[4][2];
    #pragma unroll
    for (int mt = 0; mt < 4; ++mt)
        #pragma unroll
        for (int nt = 0; nt < 2; ++nt)
            acc[mt][nt] = f32x4{0.f, 0.f, 0.f, 0.f};

    for (int k0 = 0; k0 < DB; k0 += BKB) {   // byte offset within Q row
        #pragma unroll
        for (int j = 0; j < 2; ++j) {
            async_load16(gA[j] + k0, dA[j]);
            async_load16(gB[j] + k0, dB[j]);
        }
        __syncthreads();   // drains vmcnt for the LDS-DMA

        #pragma unroll
        for (int kk = 0; kk < 2; ++kk) {     // two K=128 MFMA steps per stage
            i32x8 bf[2];
            #pragma unroll
            for (int nt = 0; nt < 2; ++nt) {
                const int r = wn + nt * 16 + fr;
                const i32x4 v = ((const i32x4*)&lB[r * BKB])[(kk * 4 + fq) ^ (r & 7)];
                bf[nt][0] = v[0]; bf[nt][1] = v[1]; bf[nt][2] = v[2]; bf[nt][3] = v[3];
                bf[nt][4] = 0;    bf[nt][5] = 0;    bf[nt][6] = 0;    bf[nt][7] = 0;
            }
            #pragma unroll
            for (int mt = 0; mt < 4; ++mt) {
                const int r = wm + mt * 16 + fr;
                const i32x4 v = ((const i32x4*)&lA[r * BKB])[(kk * 4 + fq) ^ (r & 7)];
                i32x8 af;
                af[0] = v[0]; af[1] = v[1]; af[2] = v[2]; af[3] = v[3];
                af[4] = 0;    af[5] = 0;    af[6] = 0;    af[7] = 0;
                #pragma unroll
                for (int nt = 0; nt < 2; ++nt)
                    acc[mt][nt] = __builtin_amdgcn_mfma_scale_f32_16x16x128_f8f6f4(
                        af, bf[nt], acc[mt][nt],
                        4, 4,               // cbsz=fp4, blgp=fp4
                        0, 0x7f7f7f7f,      // scale A: e8m0 127 = 1.0
                        0, 0x7f7f7f7f);     // scale B
            }
        }

        __syncthreads();   // protect LDS before next staging round
    }

    // Epilogue: g = acc/1024 (undo 32x per-operand encoding);
    // e = exp(-max(2-2g,0)/2); diag tile masks i==j; off-diag x2.
    constexpr float INV = 1.0f / 1024.0f;
    float lsum = 0.0f;
    #pragma unroll
    for (int mt = 0; mt < 4; ++mt) {
        #pragma unroll
        for (int nt = 0; nt < 2; ++nt) {
            #pragma unroll
            for (int r = 0; r < 4; ++r) {
                const float g  = acc[mt][nt][r] * INV;
                const int   gi = wm + mt * 16 + fq * 4 + r;   // local row
                const int   gj = wn + nt * 16 + fr;           // local col
                const float d2 = fmaxf(2.0f - 2.0f * g, 0.0f);
                const float e  = __expf(-0.5f * d2);
                lsum += (diag && gi == gj) ? 0.0f : e;
            }
        }
    }
    #pragma unroll
    for (int off = 32; off; off >>= 1) lsum += __shfl_down(lsum, off);
    if (lane == 0) wsum[wave] = lsum;
    __syncthreads();
    if (t == 0) {
        float s = 0.0f;
        #pragma unroll
        for (int w = 0; w < 8; ++w) s += wsum[w];
        star_part[blockIdx.x] = (diag ? 1.0f : 2.0f) * s;
    }
}

// ---------------------------------------------------------------------------
// Kernel 3: sum the partials, assemble the scalar loss.
// ---------------------------------------------------------------------------
__global__ __launch_bounds__(256) void finalize_kernel(
    const float* __restrict__ spos, const float* __restrict__ star,
    float* __restrict__ out)
{
    const int t = threadIdx.x, lane = t & 63, wave = t >> 6;
    float s1 = 0.0f, s2 = 0.0f;
    for (int i = t; i < N;    i += 256) s1 += spos[i];
    for (int i = t; i < NTRI; i += 256) s2 += star[i];
    #pragma unroll
    for (int off = 32; off; off >>= 1) {
        s1 += __shfl_down(s1, off);
        s2 += __shfl_down(s2, off);
    }
    __shared__ float r1[4], r2[4];
    if (lane == 0) { r1[wave] = s1; r2[wave] = s2; }
    __syncthreads();
    if (t == 0) {
        const float spos_sum = r1[0] + r1[1] + r1[2] + r1[3];
        const float star_sum = r2[0] + r2[1] + r2[2] + r2[3];
        const float star_mean = star_sum / ((float)N * (float)(N - 1)) + EPS;
        out[0] = -spos_sum / (float)N + ALPHA * star_mean;
    }
}

// ---------------------------------------------------------------------------
extern "C" void kernel_launch(void* const* d_in, const int* in_sizes, int n_in,
                              void* d_out, int out_size, void* d_ws, size_t ws_size,
                              hipStream_t stream)
{
    (void)in_sizes; (void)n_in; (void)out_size; (void)ws_size;
    const float* z    = (const float*)d_in[0];
    float*       out  = (float*)d_out;
    u8*          q    = (u8*)d_ws;                                   // 2 MB fp4
    float*       spos = (float*)((char*)d_ws + (size_t)N * DB);      // 4096 f
    float*       star = spos + N;                                    // 528 f

    hipLaunchKernelGGL(norm_spos_kernel, dim3(N / 4), dim3(256), 0, stream, z, q, spos);
    hipLaunchKernelGGL(gram_kernel,      dim3(NTRI),  dim3(512), 0, stream, q, star);
    hipLaunchKernelGGL(finalize_kernel,  dim3(1),     dim3(256), 0, stream, spos, star, out);
}